// Round 7
// baseline (252.503 us; speedup 1.0000x reference)
//
#include <hip/hip_runtime.h>
#include <hip/hip_cooperative_groups.h>

namespace cg = cooperative_groups;

// Problem constants: B=8, H=320, W=1024, CH=CW=3, MAXINS=200
#define BATCH   8
#define HW      (320 * 1024)        // 327680 pixels per batch
#define ELEMS   (HW * 9)            // 2949120 floats per batch
#define MAXINS  200
#define BINS    (MAXINS * 9)        // 1800 bins per batch
#define NXBLK   256                 // tiles per batch (2048 tiles total)
#define NTILES  (BATCH * NXBLK)
#define GPT     (ELEMS / 8 / NXBLK) // 1440 groups-of-8 per tile
#define SCALE      2097152.0f       // 2^21 fixed-point scale
#define INV_SCALE  (1.1f / 2097152.0f)

// Decode an 8-element group starting at e: spans at most 2 pixels (8 < 9).
__device__ __forceinline__ void decode8(int e, int& pix0, int& pix1,
                                        int& j0, int& b) {
    pix0 = e / 9;
    j0   = e - pix0 * 9;
    b    = 9 - j0;
    pix1 = (e + 7) / 9;
}

// ---------------------------------------------------------------------------
// Fused cooperative kernel: compress -> grid.sync -> reduce -> grid.sync ->
// inflate. Each block inflates the slice it compressed (inst slice L1-hot).
// ---------------------------------------------------------------------------
__global__ __launch_bounds__(256) void epp_fused(
    const int* __restrict__ inst, const float* __restrict__ src,
    int* __restrict__ part, float* __restrict__ comp, float* __restrict__ out)
{
    cg::grid_group grid = cg::this_grid();
    __shared__ int bins[BINS];
    float* fbins = (float*)bins;
    const int nblk = gridDim.x;

    // ---- Phase A: compress (per-tile LDS int32 histogram -> partials) ----
    for (int tile = blockIdx.x; tile < NTILES; tile += nblk) {
        const int b  = tile >> 8;          // tile / NXBLK
        const int xb = tile & 255;
        for (int i = threadIdx.x; i < BINS; i += 256) bins[i] = 0;
        __syncthreads();

        const int* __restrict__ instb = inst + b * HW;
        const float4* __restrict__ srcb = (const float4*)(src + (size_t)b * ELEMS);
        const int g0 = xb * GPT;

        for (int g = g0 + threadIdx.x; g < g0 + GPT; g += 256) {
            float4 v0 = srcb[2 * g];
            float4 v1 = srcb[2 * g + 1];
            const int e = g * 8;
            int pix0, pix1, j0, cnt;
            decode8(e, pix0, pix1, j0, cnt);
            const int id0 = instb[pix0] * 9 + j0;
            const int id1 = instb[pix1] * 9 + j0 - 9;
            float vals[8] = {v0.x, v0.y, v0.z, v0.w, v1.x, v1.y, v1.z, v1.w};
#pragma unroll
            for (int k = 0; k < 8; ++k) {
                int base = (k < cnt) ? id0 : id1;
                int q = __float2int_rn(vals[k] * SCALE);
                atomicAdd(&bins[base + k], q);     // native ds_add_u32
            }
        }
        __syncthreads();
        int* __restrict__ pb = part + (size_t)tile * BINS;
        for (int i = threadIdx.x; i < BINS; i += 256) pb[i] = bins[i];
        __syncthreads();
    }

    grid.sync();

    // ---- Phase B: reduce partials -> comp (first 57 blocks do the work) ----
    {
        const int o = blockIdx.x * 256 + threadIdx.x;
        if (o < BATCH * BINS) {
            const int b = o / BINS, i = o - b * BINS;
            const int* __restrict__ pb = part + (size_t)b * NXBLK * BINS + i;
            long long s0 = 0, s1 = 0, s2 = 0, s3 = 0;
#pragma unroll 4
            for (int g = 0; g < NXBLK; g += 4) {
                s0 += pb[(size_t)(g + 0) * BINS];
                s1 += pb[(size_t)(g + 1) * BINS];
                s2 += pb[(size_t)(g + 2) * BINS];
                s3 += pb[(size_t)(g + 3) * BINS];
            }
            long long s = (s0 + s1) + (s2 + s3);
            comp[o] = (float)((double)s * (double)INV_SCALE);
        }
    }

    grid.sync();

    // ---- Phase C: inflate (stage comp[b] in LDS, gather, coalesced f4) ----
    for (int tile = blockIdx.x; tile < NTILES; tile += nblk) {
        const int b  = tile >> 8;
        const int xb = tile & 255;
        const float* __restrict__ compb = comp + b * BINS;
        for (int i = threadIdx.x; i < BINS; i += 256) fbins[i] = compb[i];
        __syncthreads();

        const int* __restrict__ instb = inst + b * HW;
        float4* __restrict__ outb = (float4*)(out + (size_t)b * ELEMS);
        const int g0 = xb * GPT;

        for (int g = g0 + threadIdx.x; g < g0 + GPT; g += 256) {
            const int e = g * 8;
            int pix0, pix1, j0, cnt;
            decode8(e, pix0, pix1, j0, cnt);
            const int id0 = instb[pix0] * 9 + j0;
            const int id1 = instb[pix1] * 9 + j0 - 9;
            float vals[8];
#pragma unroll
            for (int k = 0; k < 8; ++k) {
                int base = (k < cnt) ? id0 : id1;
                vals[k] = fbins[base + k];
            }
            outb[2 * g]     = make_float4(vals[0], vals[1], vals[2], vals[3]);
            outb[2 * g + 1] = make_float4(vals[4], vals[5], vals[6], vals[7]);
        }
        __syncthreads();
    }
}

// ---------------------------------------------------------------------------
// R6 fallback path (3 kernels) — used if cooperative launch is rejected.
// ---------------------------------------------------------------------------
__global__ __launch_bounds__(256) void epp_compress(
    const int* __restrict__ inst, const float* __restrict__ src,
    int* __restrict__ part)
{
    __shared__ int bins[BINS];
    const int b = blockIdx.y;
    for (int i = threadIdx.x; i < BINS; i += 256) bins[i] = 0;
    __syncthreads();
    const int total8 = ELEMS / 8;
    const int* __restrict__ instb = inst + b * HW;
    const float4* __restrict__ srcb = (const float4*)(src + (size_t)b * ELEMS);
    const int stride = NXBLK * 256;
    for (int g = blockIdx.x * 256 + threadIdx.x; g < total8; g += stride) {
        float4 v0 = srcb[2 * g];
        float4 v1 = srcb[2 * g + 1];
        const int e = g * 8;
        int pix0, pix1, j0, cnt;
        decode8(e, pix0, pix1, j0, cnt);
        const int id0 = instb[pix0] * 9 + j0;
        const int id1 = instb[pix1] * 9 + j0 - 9;
        float vals[8] = {v0.x, v0.y, v0.z, v0.w, v1.x, v1.y, v1.z, v1.w};
#pragma unroll
        for (int k = 0; k < 8; ++k) {
            int base = (k < cnt) ? id0 : id1;
            int q = __float2int_rn(vals[k] * SCALE);
            atomicAdd(&bins[base + k], q);
        }
    }
    __syncthreads();
    int* __restrict__ pb = part + ((size_t)b * NXBLK + blockIdx.x) * BINS;
    for (int i = threadIdx.x; i < BINS; i += 256) pb[i] = bins[i];
}

__global__ __launch_bounds__(256) void epp_reduce(
    const int* __restrict__ part, float* __restrict__ comp)
{
    int o = blockIdx.x * 256 + threadIdx.x;
    if (o >= BATCH * BINS) return;
    int b = o / BINS, i = o - b * BINS;
    const int* __restrict__ pb = part + (size_t)b * NXBLK * BINS + i;
    long long s0 = 0, s1 = 0, s2 = 0, s3 = 0;
#pragma unroll 4
    for (int g = 0; g < NXBLK; g += 4) {
        s0 += pb[(size_t)(g + 0) * BINS];
        s1 += pb[(size_t)(g + 1) * BINS];
        s2 += pb[(size_t)(g + 2) * BINS];
        s3 += pb[(size_t)(g + 3) * BINS];
    }
    long long s = (s0 + s1) + (s2 + s3);
    comp[o] = (float)((double)s * (double)INV_SCALE);
}

__global__ __launch_bounds__(256) void epp_inflate(
    const int* __restrict__ inst, const float* __restrict__ comp,
    float* __restrict__ out)
{
    __shared__ float bins[BINS];
    const int b = blockIdx.y;
    const float* __restrict__ compb = comp + b * BINS;
    for (int i = threadIdx.x; i < BINS; i += 256) bins[i] = compb[i];
    __syncthreads();
    const int total8 = ELEMS / 8;
    const int* __restrict__ instb = inst + b * HW;
    float4* __restrict__ outb = (float4*)(out + (size_t)b * ELEMS);
    const int stride = gridDim.x * 256;
    for (int g = blockIdx.x * 256 + threadIdx.x; g < total8; g += stride) {
        const int e = g * 8;
        int pix0, pix1, j0, cnt;
        decode8(e, pix0, pix1, j0, cnt);
        const int id0 = instb[pix0] * 9 + j0;
        const int id1 = instb[pix1] * 9 + j0 - 9;
        float vals[8];
#pragma unroll
        for (int k = 0; k < 8; ++k) {
            int base = (k < cnt) ? id0 : id1;
            vals[k] = bins[base + k];
        }
        outb[2 * g]     = make_float4(vals[0], vals[1], vals[2], vals[3]);
        outb[2 * g + 1] = make_float4(vals[4], vals[5], vals[6], vals[7]);
    }
}

extern "C" void kernel_launch(void* const* d_in, const int* in_sizes, int n_in,
                              void* d_out, int out_size, void* d_ws, size_t ws_size,
                              hipStream_t stream) {
    const int*   inst = (const int*)d_in[0];    // [B,1,H,W] int32
    const float* src  = (const float*)d_in[1];  // [B,H,W,3,3] f32
    float* out = (float*)d_out;                 // [B,H,W,3,3] f32

    const size_t compBytes = (size_t)BATCH * BINS * sizeof(float);       // 57.6 KB
    const size_t partBytes = (size_t)NTILES * BINS * sizeof(int);        // 14.7 MB

    if (ws_size < partBytes + compBytes) {
        // Tiny-ws emergency path: shouldn't happen (ws has been >= 300MB).
        return;
    }

    int*   part = (int*)d_ws;
    float* comp = (float*)(part + (size_t)NTILES * BINS);

    // Co-resident grid sizing for the cooperative launch (pure host queries).
    int blocksPerCU = 0;
    hipError_t qe = hipOccupancyMaxActiveBlocksPerMultiprocessor(
        &blocksPerCU, epp_fused, 256, 0);
    int nblk = (qe == hipSuccess) ? blocksPerCU * 256 : 0;  // 256 CUs on MI355X
    if (nblk > NTILES) nblk = NTILES;

    bool launched = false;
    if (nblk >= 256) {
        void* args[] = {(void*)&inst, (void*)&src, (void*)&part,
                        (void*)&comp, (void*)&out};
        hipError_t le = hipLaunchCooperativeKernel(
            (const void*)epp_fused, dim3(nblk), dim3(256), args, 0, stream);
        if (le == hipSuccess) {
            launched = true;
        } else {
            (void)hipGetLastError();   // clear sticky error, fall back
        }
    }

    if (!launched) {
        // Proven R6 3-kernel path.
        dim3 cgrid(NXBLK, BATCH);
        epp_compress<<<cgrid, 256, 0, stream>>>(inst, src, part);
        int rblocks = (BATCH * BINS + 255) / 256;
        epp_reduce<<<rblocks, 256, 0, stream>>>(part, comp);
        dim3 igrid(512, BATCH);
        epp_inflate<<<igrid, 256, 0, stream>>>(inst, comp, out);
    }
}

// Round 8
// 56.087 us; speedup vs baseline: 4.5020x; 4.5020x over previous
//
#include <hip/hip_runtime.h>

// Problem constants: B=8, H=320, W=1024, CH=CW=3, MAXINS=200
#define BATCH   8
#define HW      (320 * 1024)        // 327680 pixels per batch
#define ELEMS   (HW * 9)            // 2949120 floats per batch
#define MAXINS  200
#define BINS    (MAXINS * 9)        // 1800 bins per batch
#define NXBLK   256                 // compress x-blocks per batch (2048 blocks = 8/CU)
#define SCALE      2097152.0f       // 2^21 fixed-point scale
#define INV_SCALE_D (1.1 / 2097152.0)   // double: fold 1.1 into the unscale

// Decode an 8-element group starting at e: spans at most 2 pixels (8 < 9).
// 2 id loads + 2 divs per 8 elements.
__device__ __forceinline__ void decode8(int e, int& pix0, int& pix1,
                                        int& j0, int& b) {
    pix0 = e / 9;             // compiler magic-mul
    j0   = e - pix0 * 9;
    b    = 9 - j0;
    pix1 = (e + 7) / 9;       // == pix0 when b >= 8
}

// ---------------------------------------------------------------------------
// Compress: per-block LDS histogram in fixed-point int32 (native ds_add;
// float LDS atomicAdd CAS-expands — that was the original 130us wall).
// Flush: global atomicAdd(int) straight into comp[b] — native integer RMW,
// no partials buffer, no reduce kernel, no extra launch gap.
// ---------------------------------------------------------------------------
__global__ __launch_bounds__(256) void epp_compress(
    const int* __restrict__ inst, const float* __restrict__ src,
    int* __restrict__ compi)
{
    __shared__ int bins[BINS];
    const int b = blockIdx.y;

    for (int i = threadIdx.x; i < BINS; i += 256) bins[i] = 0;
    __syncthreads();

    const int total8 = ELEMS / 8;                    // 368640 groups/batch
    const int* __restrict__ instb = inst + b * HW;
    const float4* __restrict__ srcb = (const float4*)(src + (size_t)b * ELEMS);
    const int stride = NXBLK * 256;

    for (int g = blockIdx.x * 256 + threadIdx.x; g < total8; g += stride) {
        float4 v0 = srcb[2 * g];
        float4 v1 = srcb[2 * g + 1];
        const int e = g * 8;
        int pix0, pix1, j0, cnt;
        decode8(e, pix0, pix1, j0, cnt);
        const int id0 = instb[pix0] * 9 + j0;        // LDS base for pix0 run
        const int id1 = instb[pix1] * 9 + j0 - 9;    // LDS base for pix1 run
        float vals[8] = {v0.x, v0.y, v0.z, v0.w, v1.x, v1.y, v1.z, v1.w};
#pragma unroll
        for (int k = 0; k < 8; ++k) {
            int base = (k < cnt) ? id0 : id1;
            int q = __float2int_rn(vals[k] * SCALE);
            atomicAdd(&bins[base + k], q);           // ds_add_u32 (native)
        }
    }
    __syncthreads();

    // Direct global int-atomic flush (coalesced addresses across lanes;
    // 256 colliding blocks per address, resolved in L2/fabric).
    int* __restrict__ cb = compi + b * BINS;
    for (int i = threadIdx.x; i < BINS; i += 256) {
        atomicAdd(&cb[i], bins[i]);
    }
}

// ---------------------------------------------------------------------------
// Inflate: stage per-batch int table in LDS (converting to float with the
// 1.1/SCALE factor folded in), gather, plain coalesced float4 stores.
// ---------------------------------------------------------------------------
__global__ __launch_bounds__(256) void epp_inflate(
    const int* __restrict__ inst, const int* __restrict__ compi,
    float* __restrict__ out)
{
    __shared__ float bins[BINS];
    const int b = blockIdx.y;
    const int* __restrict__ cb = compi + b * BINS;
    for (int i = threadIdx.x; i < BINS; i += 256) {
        bins[i] = (float)((double)cb[i] * INV_SCALE_D);
    }
    __syncthreads();

    const int total8 = ELEMS / 8;
    const int* __restrict__ instb = inst + b * HW;
    float4* __restrict__ outb = (float4*)(out + (size_t)b * ELEMS);
    const int stride = gridDim.x * 256;

    for (int g = blockIdx.x * 256 + threadIdx.x; g < total8; g += stride) {
        const int e = g * 8;
        int pix0, pix1, j0, cnt;
        decode8(e, pix0, pix1, j0, cnt);
        const int id0 = instb[pix0] * 9 + j0;
        const int id1 = instb[pix1] * 9 + j0 - 9;
        float vals[8];
#pragma unroll
        for (int k = 0; k < 8; ++k) {
            int base = (k < cnt) ? id0 : id1;
            vals[k] = bins[base + k];
        }
        outb[2 * g]     = make_float4(vals[0], vals[1], vals[2], vals[3]);
        outb[2 * g + 1] = make_float4(vals[4], vals[5], vals[6], vals[7]);
    }
}

extern "C" void kernel_launch(void* const* d_in, const int* in_sizes, int n_in,
                              void* d_out, int out_size, void* d_ws, size_t ws_size,
                              hipStream_t stream) {
    const int*   inst = (const int*)d_in[0];    // [B,1,H,W] int32
    const float* src  = (const float*)d_in[1];  // [B,H,W,3,3] f32
    float* out = (float*)d_out;                 // [B,H,W,3,3] f32

    const size_t compBytes = (size_t)BATCH * BINS * sizeof(int);   // 57.6 KB
    if (ws_size < compBytes) return;            // ws has always been >= 300MB

    int* compi = (int*)d_ws;

    // Zero the int accumulator every call (graph-safe, ~57.6 KB).
    (void)hipMemsetAsync(compi, 0, compBytes, stream);

    dim3 cgrid(NXBLK, BATCH);                   // 2048 blocks, 8/CU, 32 waves/CU
    epp_compress<<<cgrid, 256, 0, stream>>>(inst, src, compi);

    dim3 igrid(512, BATCH);                     // 4096 blocks
    epp_inflate<<<igrid, 256, 0, stream>>>(inst, compi, out);
}